// Round 1
// baseline (463.459 us; speedup 1.0000x reference)
//
#include <hip/hip_runtime.h>
#include <stdint.h>

#define B_DIM 4096
#define IN_SZ 1024
#define HID   2048
#define D_DIM 3072   // K = IN_SZ + HID
#define BM 128       // rows (batch) per block
#define BH 32        // h-columns per gate per block (x4 gates = 128 cols)
#define BK 32        // K-step (bf16 elems)

typedef float  f32x4  __attribute__((ext_vector_type(4)));
typedef short  short8 __attribute__((ext_vector_type(8)));

__device__ __forceinline__ unsigned short f2bf(float f) {
    union { float f; unsigned u; } v; v.f = f;
    unsigned u = v.u + 0x7fffu + ((v.u >> 16) & 1u);   // RNE
    return (unsigned short)(u >> 16);
}

__device__ __forceinline__ void async_load16(const void* g, void* l) {
    __builtin_amdgcn_global_load_lds(
        (const __attribute__((address_space(1))) unsigned int*)g,
        (__attribute__((address_space(3))) unsigned int*)l,
        16, 0, 0);
}

__device__ __forceinline__ float sigm(float x) {
    return 1.0f / (1.0f + __expf(-x));          // large -x -> exp=inf -> 0, safe
}
__device__ __forceinline__ float tanh_f(float x) {
    return 1.0f - 2.0f / (__expf(2.0f * x) + 1.0f);  // +inf-safe both sides
}

// ---- prepass: concat(x_t, h_prev) -> bf16 [B][D] ----
__global__ void convert_combined(const float* __restrict__ x,
                                 const float* __restrict__ h,
                                 unsigned short* __restrict__ dst) {
    int idx = blockIdx.x * blockDim.x + threadIdx.x;       // float4 index
    const int C4 = D_DIM / 4;                              // 768
    if (idx >= B_DIM * C4) return;
    int b  = idx / C4;
    int c4 = idx - b * C4;
    float4 v;
    if (c4 < IN_SZ / 4) v = ((const float4*)x)[b * (IN_SZ / 4) + c4];
    else                v = ((const float4*)h)[b * (HID / 4) + (c4 - IN_SZ / 4)];
    ushort4 o;
    o.x = f2bf(v.x); o.y = f2bf(v.y); o.z = f2bf(v.z); o.w = f2bf(v.w);
    ((ushort4*)dst)[idx] = o;
}

// ---- prepass: concat(W_i,W_f,W_c,W_o) -> bf16 [4H][D] ----
__global__ void convert_W(const float* __restrict__ W0, const float* __restrict__ W1,
                          const float* __restrict__ W2, const float* __restrict__ W3,
                          unsigned short* __restrict__ dst) {
    int idx = blockIdx.x * blockDim.x + threadIdx.x;       // float4 index
    const int PG = HID * D_DIM / 4;                        // per-gate float4 count
    if (idx >= 4 * PG) return;
    int g = idx / PG;
    int r = idx - g * PG;
    const float* W = (g == 0) ? W0 : (g == 1) ? W1 : (g == 2) ? W2 : W3;
    float4 v = ((const float4*)W)[r];
    ushort4 o;
    o.x = f2bf(v.x); o.y = f2bf(v.y); o.z = f2bf(v.z); o.w = f2bf(v.w);
    ((ushort4*)dst)[idx] = o;
}

// ---- fused gate-GEMM + LSTM epilogue ----
// block: 256 threads (4 waves). Block tile: BM=128 rows x (4 gates x BH=32) cols.
// Wave w: rows [w*32, w*32+32), all 128 cols -> 2x8 16x16 C-fragments.
// Col n in [0,128): gate = n>>5, h = h0 + (n&31)  => all 4 gates of an h share a lane.
__global__ __launch_bounds__(256, 2)
void lstm_gemm(const unsigned short* __restrict__ Abf,   // [B][D] bf16
               const unsigned short* __restrict__ Wbf,   // [4H][D] bf16
               const float* __restrict__ b_i, const float* __restrict__ b_f,
               const float* __restrict__ b_c, const float* __restrict__ b_o,
               const float* __restrict__ c_prev,         // [B][HID] f32
               float* __restrict__ h_out, float* __restrict__ c_out) {
    __shared__ unsigned short sA[BM * BK];   // 8 KB
    __shared__ unsigned short sB[BM * BK];   // 8 KB (4 gates x 32 rows)

    const int tid  = threadIdx.x;
    const int lane = tid & 63;
    const int wave = tid >> 6;
    const int l16  = lane & 15;
    const int quad = lane >> 4;

    const int m0 = blockIdx.x * BM;
    const int h0 = blockIdx.y * BH;

    f32x4 acc[2][8] = {};   // [row-tile][col-tile]

    // staging lane mapping: 1 KB per global_load_lds = 16 rows x 64 B
    const int srow = lane >> 2;            // 0..15
    const int scol = (lane & 3) * 8;       // bf16 elems (16 B chunks)
    const unsigned short* gA = Abf + (size_t)(m0 + wave * 32 + srow) * D_DIM + scol;
    // wave w stages gate w's 32 rows: W row = w*HID + h0 + row_in_gate
    const unsigned short* gB = Wbf + (size_t)(wave * HID + h0 + srow) * D_DIM + scol;
    unsigned short* lA0 = &sA[(wave * 32) * BK];
    unsigned short* lA1 = &sA[(wave * 32 + 16) * BK];
    unsigned short* lB0 = &sB[(wave * 32) * BK];
    unsigned short* lB1 = &sB[(wave * 32 + 16) * BK];

    for (int kk = 0; kk < D_DIM / BK; ++kk) {
        const int k0 = kk * BK;
        if (kk) __syncthreads();           // protect LDS still being read
        async_load16(gA + k0,                 lA0 + lane * 8);
        async_load16(gA + 16 * D_DIM + k0,    lA1 + lane * 8);
        async_load16(gB + k0,                 lB0 + lane * 8);
        async_load16(gB + 16 * D_DIM + k0,    lB1 + lane * 8);
        __syncthreads();                   // compiler drains vmcnt before barrier

        short8 a0 = *(const short8*)&sA[(wave * 32 + l16) * BK + quad * 8];
        short8 a1 = *(const short8*)&sA[(wave * 32 + 16 + l16) * BK + quad * 8];
#pragma unroll
        for (int ct = 0; ct < 8; ++ct) {
            short8 b = *(const short8*)&sB[(ct * 16 + l16) * BK + quad * 8];
            acc[0][ct] = __builtin_amdgcn_mfma_f32_16x16x32_bf16(a0, b, acc[0][ct], 0, 0, 0);
            acc[1][ct] = __builtin_amdgcn_mfma_f32_16x16x32_bf16(a1, b, acc[1][ct], 0, 0, 0);
        }
    }

    // epilogue: C layout col = lane&15, row = quad*4 + reg
    const int rbase = m0 + wave * 32 + quad * 4;
#pragma unroll
    for (int cj = 0; cj < 2; ++cj) {
        const int h  = h0 + cj * 16 + l16;
        const float bi = b_i[h], bf = b_f[h], bc = b_c[h], bo = b_o[h];
#pragma unroll
        for (int rt = 0; rt < 2; ++rt) {
#pragma unroll
            for (int r = 0; r < 4; ++r) {
                const int m = rbase + rt * 16 + r;
                const size_t off = (size_t)m * HID + h;
                float gi = acc[rt][0 + cj][r] + bi;
                float gf = acc[rt][2 + cj][r] + bf;
                float gc = acc[rt][4 + cj][r] + bc;
                float go = acc[rt][6 + cj][r] + bo;
                float it = sigm(gi);
                float ft = sigm(gf);
                float gt = tanh_f(gc);
                float ot = sigm(go);
                float c  = ft * c_prev[off] + it * gt;
                float hv = ot * tanh_f(c);
                h_out[off] = hv;
                c_out[off] = c;
            }
        }
    }
}

extern "C" void kernel_launch(void* const* d_in, const int* in_sizes, int n_in,
                              void* d_out, int out_size, void* d_ws, size_t ws_size,
                              hipStream_t stream) {
    const float* x_t    = (const float*)d_in[0];
    const float* h_prev = (const float*)d_in[1];
    const float* c_prev = (const float*)d_in[2];
    const float* W_i = (const float*)d_in[3];
    const float* b_i = (const float*)d_in[4];
    const float* W_f = (const float*)d_in[5];
    const float* b_f = (const float*)d_in[6];
    const float* W_c = (const float*)d_in[7];
    const float* b_c = (const float*)d_in[8];
    const float* W_o = (const float*)d_in[9];
    const float* b_o = (const float*)d_in[10];
    float* out = (float*)d_out;

    unsigned short* Abf = (unsigned short*)d_ws;                       // 25,165,824 B
    unsigned short* Wbf = (unsigned short*)((char*)d_ws + (size_t)B_DIM * D_DIM * 2);
    // total ws use: 75,497,472 B

    {
        int n = B_DIM * D_DIM / 4;
        convert_combined<<<(n + 255) / 256, 256, 0, stream>>>(x_t, h_prev, Abf);
    }
    {
        int n = 4 * HID * D_DIM / 4;
        convert_W<<<(n + 255) / 256, 256, 0, stream>>>(W_i, W_f, W_c, W_o, Wbf);
    }
    dim3 grid(B_DIM / BM, HID / BH);   // 32 x 64
    lstm_gemm<<<grid, 256, 0, stream>>>(Abf, Wbf, b_i, b_f, b_c, b_o, c_prev,
                                        out, out + (size_t)B_DIM * HID);
}